// Round 1
// baseline (5169.410 us; speedup 1.0000x reference)
//
#include <hip/hip_runtime.h>
#include <stdint.h>

// GRUClassifier: B=128, T=512, V=50000, D=U=256, 3U=768
// Design: persistent pipelined kernel, 64 blocks = 8 groups (16 samples each)
//   x 8 stages (xp0,rec0,xp1,rec1,xp2,rec2,xp3,rec3).
// xp stage l: xp_t = x_t @ Wx_l + bx (+bh folded for z/r cols); Wx resident in VGPRs.
// rec stage l: rec_t = h @ Wh_l (+bh for hh cols); gates fp32; Wh resident in VGPRs.
// Cross-block streaming via rings in d_ws with relaxed agent-scope atomics.

#define TT 512
#define RX 16   // xp ring depth (steps)
#define RH 64   // h ring depth (steps)

typedef __bf16 bf16x8 __attribute__((ext_vector_type(8)));
typedef float f32x4 __attribute__((ext_vector_type(4)));

#define FLAGS_BYTES (128*256)
#define XPRING_E ((size_t)RX*768*16)      // bf16 elems per (g,l)
#define HRING_E  ((size_t)RH*16*256)      // bf16 elems per (g,l)
#define WS_XP_OFF ((size_t)FLAGS_BYTES)
#define WS_H_OFF  (WS_XP_OFF + (size_t)32*XPRING_E*2)
#define WS_HF_OFF (WS_H_OFF  + (size_t)32*HRING_E*2)

struct Params {
  const int* tokens;
  const float* emb;
  const float* Wx[4];
  const float* Wh[4];
  const float* bx[4];
  const float* bh[4];
  uint8_t* ws;
};

#define SCOPE_AGENT __HIP_MEMORY_SCOPE_AGENT

__device__ __forceinline__ uint32_t* flagp(uint8_t* ws, int kind, int g, int l){
  return (uint32_t*)(ws + ((size_t)(kind*32 + g*4 + l) * 256));
}
__device__ __forceinline__ uint32_t aload(uint32_t* p){
  return __hip_atomic_load(p, __ATOMIC_RELAXED, SCOPE_AGENT);
}
__device__ __forceinline__ void astore(uint32_t* p, uint32_t v){
  __hip_atomic_store(p, v, __ATOMIC_RELAXED, SCOPE_AGENT);
}
__device__ __forceinline__ unsigned long long aload64(const void* p){
  return __hip_atomic_load((const unsigned long long*)p, __ATOMIC_RELAXED, SCOPE_AGENT);
}
__device__ __forceinline__ void astore64(void* p, unsigned long long v){
  __hip_atomic_store((unsigned long long*)p, v, __ATOMIC_RELAXED, SCOPE_AGENT);
}
__device__ __forceinline__ unsigned short f2b(float f){
  __bf16 b = (__bf16)f; unsigned short u; __builtin_memcpy(&u, &b, 2); return u;
}
__device__ __forceinline__ float b2f(unsigned short u){
  __bf16 b; __builtin_memcpy(&b, &u, 2); return (float)b;
}
__device__ __forceinline__ f32x4 up4(unsigned long long q){
  f32x4 r;
  #pragma unroll
  for (int i=0;i<4;++i) r[i] = b2f((unsigned short)(q >> (16*i)));
  return r;
}
__device__ __forceinline__ unsigned long long pk4(f32x4 v){
  unsigned long long q = 0;
  #pragma unroll
  for (int i=0;i<4;++i) q |= ((unsigned long long)f2b(v[i])) << (16*i);
  return q;
}
__device__ __forceinline__ float sigf(float x){ return 1.f/(1.f + __expf(-x)); }
__device__ __forceinline__ float tanh_(float x){ return 2.f/(1.f + __expf(-2.f*x)) - 1.f; }

__global__ __launch_bounds__(512, 2) void gru_pipeline(Params p){
  const int bid = blockIdx.x;
  const int g = bid >> 3;          // group: samples [16g, 16g+16)
  const int s = bid & 7;           // stage slot
  const int l = s >> 1;            // layer
  const bool isXp = (s & 1) == 0;
  const int tid = threadIdx.x;
  const int w = tid >> 6;          // wave 0..7
  const int lane = tid & 63;
  const int lg = lane >> 4;        // k-subgroup 0..3
  const int lc = lane & 15;        // row/col selector

  __shared__ int dead;
  if (tid == 0) dead = 0;
  int budget = 1 << 22;            // anti-deadlock poll budget

  if (isXp) {
    // ---------------- XP stage: xp = x @ Wx + (bx [+bh for z/r]) ----------------
    const float* W = p.Wx[l];
    bf16x8 wx[6][8];               // wave owns cols [w*96, w*96+96): 6 n-tiles
    #pragma unroll
    for (int nt=0; nt<6; ++nt){
      const int col = w*96 + nt*16 + lc;
      #pragma unroll
      for (int kt=0; kt<8; ++kt){
        const int k0 = kt*32 + lg*8;
        bf16x8 v;
        #pragma unroll
        for (int e=0; e<8; ++e) v[e] = (__bf16)W[(size_t)(k0+e)*768 + col];
        wx[nt][kt] = v;
      }
    }
    float bias[6];
    #pragma unroll
    for (int nt=0; nt<6; ++nt){
      const int col = w*96 + nt*16 + lc;
      bias[nt] = p.bx[l][col] + (col < 512 ? p.bh[l][col] : 0.f); // fold bh into z/r
    }
    uint32_t* prodXp = flagp(p.ws, 0, g, l);
    uint32_t* prodH  = (l>0) ? flagp(p.ws, 1, g, l-1) : nullptr;
    uint32_t* consXp = flagp(p.ws, 2, g, l);
    uint32_t* consH  = (l>0) ? flagp(p.ws, 3, g, l-1) : nullptr;
    __bf16* xr = (__bf16*)(p.ws + WS_XP_OFF) + (size_t)(g*4+l)*XPRING_E;
    const __bf16* hr = (l>0) ? ((const __bf16*)(p.ws + WS_H_OFF) + (size_t)(g*4+(l-1))*HRING_E) : nullptr;
    const int* tokrow = p.tokens + (size_t)(g*16+lc)*TT;
    uint32_t consSeen = 0, prodSeen = 0;
    __syncthreads();

    for (int t=0; t<TT; ++t){
      if (w == 0){
        if (l > 0){
          while (prodSeen < (uint32_t)(t+1)){
            prodSeen = aload(prodH);
            if (prodSeen < (uint32_t)(t+1)){ if(--budget<0){dead=1;break;} __builtin_amdgcn_s_sleep(2); }
          }
        }
        if (t >= RX){
          while (consSeen < (uint32_t)(t - RX + 1)){
            consSeen = aload(consXp);
            if (consSeen < (uint32_t)(t - RX + 1)){ if(--budget<0){dead=1;break;} __builtin_amdgcn_s_sleep(2); }
          }
        }
      }
      __syncthreads();              // also drains last iteration's ring stores
      if (dead) break;
      if (tid == 0 && t > 0) astore(prodXp, (uint32_t)t);  // slot t-1 is now drained

      // A-fragments of x_t (row = lc, k = kt*32 + lg*8 + e)
      bf16x8 a[8];
      if (l == 0){
        const int tok = tokrow[t];
        const float* er = p.emb + (size_t)tok*256;
        #pragma unroll
        for (int kt=0; kt<8; ++kt){
          const float4 u0 = *(const float4*)(er + kt*32 + lg*8);
          const float4 u1 = *(const float4*)(er + kt*32 + lg*8 + 4);
          bf16x8 v;
          v[0]=(__bf16)u0.x; v[1]=(__bf16)u0.y; v[2]=(__bf16)u0.z; v[3]=(__bf16)u0.w;
          v[4]=(__bf16)u1.x; v[5]=(__bf16)u1.y; v[6]=(__bf16)u1.z; v[7]=(__bf16)u1.w;
          a[kt] = v;
        }
      } else {
        const unsigned long long* hb = (const unsigned long long*)(hr + ((size_t)(t & (RH-1))*16 + lc)*256);
        #pragma unroll
        for (int kt=0; kt<8; ++kt){
          union { unsigned long long q[2]; bf16x8 v; } fb;
          fb.q[0] = aload64(hb + (kt*32 + lg*8)/4);
          fb.q[1] = aload64(hb + (kt*32 + lg*8)/4 + 1);
          a[kt] = fb.v;
        }
      }
      f32x4 acc[6];
      #pragma unroll
      for (int nt=0; nt<6; ++nt) acc[nt] = (f32x4){bias[nt],bias[nt],bias[nt],bias[nt]};
      #pragma unroll
      for (int kt=0; kt<8; ++kt){
        #pragma unroll
        for (int nt=0; nt<6; ++nt)
          acc[nt] = __builtin_amdgcn_mfma_f32_16x16x32_bf16(a[kt], wx[nt][kt], acc[nt], 0, 0, 0);
      }
      // store xp slot t: layout [slot][col][m], 4 bf16 per lane per tile
      unsigned long long* dst = (unsigned long long*)(xr + (size_t)(t & (RX-1))*768*16);
      #pragma unroll
      for (int nt=0; nt<6; ++nt){
        const int col = w*96 + nt*16 + lc;
        astore64(dst + (col*16 + lg*4)/4, pk4(acc[nt]));
      }
      if (l > 0 && tid == 0) astore(consH, (uint32_t)(t+1));
    }
    __syncthreads();
    if (tid == 0 && !dead){
      astore(prodXp, (uint32_t)TT);
      if (l > 0) astore(consH, (uint32_t)TT);
    }
  } else {
    // ---------------- REC stage: rec = h @ Wh (+bh for hh); gates; h update ----------------
    const float* W = p.Wh[l];
    // wave owns hidden slice j in [w*32, w*32+32): tiles nt = 2*G+q (G: 0=z,1=r,2=hh)
    bf16x8 wh[6][8];
    #pragma unroll
    for (int nt=0; nt<6; ++nt){
      const int col = 256*(nt>>1) + w*32 + 16*(nt&1) + lc;
      #pragma unroll
      for (int kt=0; kt<8; ++kt){
        const int k0 = kt*32 + lg*8;
        bf16x8 v;
        #pragma unroll
        for (int e=0; e<8; ++e) v[e] = (__bf16)W[(size_t)(k0+e)*768 + col];
        wh[nt][kt] = v;
      }
    }
    float bhh[2];
    #pragma unroll
    for (int q=0; q<2; ++q) bhh[q] = p.bh[l][512 + w*32 + 16*q + lc];

    uint32_t* prodXp = flagp(p.ws, 0, g, l);
    uint32_t* prodH  = (l<3) ? flagp(p.ws, 1, g, l) : nullptr;
    uint32_t* consXp = flagp(p.ws, 2, g, l);
    uint32_t* consH  = (l<3) ? flagp(p.ws, 3, g, l) : nullptr;
    const __bf16* xr = (const __bf16*)(p.ws + WS_XP_OFF) + (size_t)(g*4+l)*XPRING_E;
    __bf16* hrw = (l<3) ? ((__bf16*)(p.ws + WS_H_OFF) + (size_t)(g*4+l)*HRING_E) : nullptr;
    float* hf = (float*)(p.ws + WS_HF_OFF);

    __shared__ __align__(16) unsigned short h_lds[16*256];   // h_{t-1}, XOR-swizzled
    for (int i=tid; i<2048; i+=512) ((uint32_t*)h_lds)[i] = 0;

    f32x4 hprev[2] = {(f32x4){0.f,0.f,0.f,0.f},(f32x4){0.f,0.f,0.f,0.f}};
    uint32_t consSeen = 0, prodSeen = 0;
    __syncthreads();

    for (int t=0; t<TT; ++t){
      if (w == 0){
        while (prodSeen < (uint32_t)(t+1)){
          prodSeen = aload(prodXp);
          if (prodSeen < (uint32_t)(t+1)){ if(--budget<0){dead=1;break;} __builtin_amdgcn_s_sleep(2); }
        }
        if (l < 3 && t > RH){
          while (consSeen < (uint32_t)(t - RH)){
            consSeen = aload(consH);
            if (consSeen < (uint32_t)(t - RH)){ if(--budget<0){dead=1;break;} __builtin_amdgcn_s_sleep(2); }
          }
        }
      }
      __syncthreads();
      if (dead) break;

      // xp loads for slot t (atomic: coherent across XCDs)
      const unsigned long long* xb = (const unsigned long long*)(xr + (size_t)(t & (RX-1))*768*16);
      unsigned long long xpld[6];
      #pragma unroll
      for (int nt=0; nt<6; ++nt){
        const int col = 256*(nt>>1) + w*32 + 16*(nt&1) + lc;
        xpld[nt] = aload64(xb + (col*16 + lg*4)/4);
      }
      // export h(t-1) to h-ring (stores complete under MFMA; published next step)
      if (l < 3 && t > 0){
        unsigned long long* hd = (unsigned long long*)(hrw + ((size_t)((t-1) & (RH-1))*16 + lc)*256);
        #pragma unroll
        for (int kt=0; kt<8; ++kt){
          #pragma unroll
          for (int hh=0; hh<2; ++hh){
            const int idx = (lc*256 + kt*32 + lg*8 + hh*4) ^ ((lc&7)<<3);
            astore64(hd + (kt*32 + lg*8 + hh*4)/4, *(const unsigned long long*)&h_lds[idx]);
          }
        }
      }
      // acc init: z/r tiles from xp (bx+bh folded), hh tiles = bh only
      f32x4 acc[6];
      #pragma unroll
      for (int nt=0; nt<4; ++nt) acc[nt] = up4(xpld[nt]);
      #pragma unroll
      for (int q=0; q<2; ++q) acc[4+q] = (f32x4){bhh[q],bhh[q],bhh[q],bhh[q]};
      // MFMA over K=256 with rolling A-frag reads from swizzled LDS
      {
        bf16x8 acur, anext;
        { const int idx0 = (lc*256 + lg*8) ^ ((lc&7)<<3);
          acur = *(const bf16x8*)&h_lds[idx0]; }
        #pragma unroll
        for (int kt=0; kt<8; ++kt){
          if (kt < 7){
            const int idx = (lc*256 + (kt+1)*32 + lg*8) ^ ((lc&7)<<3);
            anext = *(const bf16x8*)&h_lds[idx];
          }
          #pragma unroll
          for (int nt=0; nt<6; ++nt)
            acc[nt] = __builtin_amdgcn_mfma_f32_16x16x32_bf16(acur, wh[nt][kt], acc[nt], 0, 0, 0);
          acur = anext;
        }
      }
      // gates (fp32): z = sig(xz+rz), r = sig(xr+rr), hh = tanh(xh + r*rh)
      f32x4 xph[2];
      xph[0] = up4(xpld[4]); xph[1] = up4(xpld[5]);
      #pragma unroll
      for (int q=0; q<2; ++q){
        #pragma unroll
        for (int e=0; e<4; ++e){
          const float z = sigf(acc[q][e]);
          const float r = sigf(acc[2+q][e]);
          const float c = tanh_(xph[q][e] + r*acc[4+q][e]);
          hprev[q][e] = z*hprev[q][e] + (1.f - z)*c;
        }
      }
      __syncthreads();   // all LDS reads (A-frags + ring export) done; xp loads drained
      // write h(t) into LDS (swizzled)
      #pragma unroll
      for (int q=0; q<2; ++q){
        const int j = w*32 + 16*q + lc;
        #pragma unroll
        for (int r=0; r<4; ++r){
          const int m = lg*4 + r;
          const int idx = (m*256 + j) ^ ((m&7)<<3);
          h_lds[idx] = f2b(hprev[q][r]);
        }
      }
      if (l == 3 && t == TT-1){
        #pragma unroll
        for (int q=0; q<2; ++q){
          const int j = w*32 + 16*q + lc;
          #pragma unroll
          for (int r=0; r<4; ++r) hf[(size_t)(g*16 + lg*4 + r)*256 + j] = hprev[q][r];
        }
      }
      __syncthreads();
      if (tid == 0){
        if (l < 3 && t > 0) astore(prodH, (uint32_t)t);  // slot t-1 ready (drained above)
        astore(consXp, (uint32_t)(t+1));
      }
    }
    if (!dead){
      if (l < 3){
        // export final h(511) and publish
        unsigned long long* hd = (unsigned long long*)(hrw + ((size_t)((TT-1) & (RH-1))*16 + lc)*256);
        #pragma unroll
        for (int kt=0; kt<8; ++kt){
          #pragma unroll
          for (int hh=0; hh<2; ++hh){
            const int idx = (lc*256 + kt*32 + lg*8 + hh*4) ^ ((lc&7)<<3);
            astore64(hd + (kt*32 + lg*8 + hh*4)/4, *(const unsigned long long*)&h_lds[idx]);
          }
        }
        __syncthreads();   // drain
        if (tid == 0) astore(prodH, (uint32_t)TT);
      }
      if (tid == 0) astore(consXp, (uint32_t)TT);
    }
  }
}

// Final head: relu(h @ Wd1 + bd1) @ Wd2 + bd2 -> sigmoid. One block per sample.
__global__ __launch_bounds__(256) void dense_head(const float* __restrict__ hf,
    const float* __restrict__ Wd1, const float* __restrict__ bd1,
    const float* __restrict__ Wd2, const float* __restrict__ bd2,
    float* __restrict__ out){
  const int m = blockIdx.x;
  const int n = threadIdx.x;
  __shared__ float hs[256];
  __shared__ float red[256];
  hs[n] = hf[(size_t)m*256 + n];
  __syncthreads();
  float acc = bd1[n];
  #pragma unroll 8
  for (int k=0; k<256; ++k) acc = fmaf(hs[k], Wd1[(size_t)k*256 + n], acc);
  const float rl = fmaxf(acc, 0.f);
  red[n] = rl * Wd2[n];
  __syncthreads();
  for (int off=128; off>0; off>>=1){
    if (n < off) red[n] += red[n+off];
    __syncthreads();
  }
  if (n == 0) out[m] = 1.f/(1.f + __expf(-(red[0] + bd2[0])));
}

extern "C" void kernel_launch(void* const* d_in, const int* in_sizes, int n_in,
                              void* d_out, int out_size, void* d_ws, size_t ws_size,
                              hipStream_t stream){
  (void)in_sizes; (void)n_in; (void)out_size; (void)ws_size;
  Params p;
  p.tokens = (const int*)d_in[0];
  p.emb    = (const float*)d_in[1];
  for (int l=0; l<4; ++l){
    p.Wx[l] = (const float*)d_in[2+4*l];
    p.Wh[l] = (const float*)d_in[3+4*l];
    p.bx[l] = (const float*)d_in[4+4*l];
    p.bh[l] = (const float*)d_in[5+4*l];
  }
  p.ws = (uint8_t*)d_ws;
  hipMemsetAsync(d_ws, 0, FLAGS_BYTES, stream);           // zero flags each launch
  gru_pipeline<<<dim3(64), dim3(512), 0, stream>>>(p);
  dense_head<<<dim3(128), dim3(256), 0, stream>>>(
      (const float*)((uint8_t*)d_ws + WS_HF_OFF),
      (const float*)d_in[18], (const float*)d_in[19],
      (const float*)d_in[20], (const float*)d_in[21],
      (float*)d_out);
}

// Round 2
// 2903.654 us; speedup vs baseline: 1.7803x; 1.7803x over previous
//
#include <hip/hip_runtime.h>
#include <stdint.h>

// GRUClassifier: B=128, T=512, V=50000, D=U=256, 3U=768
// Persistent pipelined kernel, 64 blocks = 8 groups (16 samples) x 8 stages
// (xp0,rec0,...,xp3,rec3). Flags: 4B agent atomics (tid0 only). Ring DATA:
// wide coherent loads/stores (global_*_dwordx2/x4 sc0 sc1) -> coalesced,
// cache-bypassing to the coherence point (no per-lane atomic transactions).

#define TT 512
#define RX 16   // xp ring depth (steps)
#define RH 64   // h ring depth (steps)

typedef __bf16 bf16x8 __attribute__((ext_vector_type(8)));
typedef float f32x4 __attribute__((ext_vector_type(4)));
typedef int i32x4 __attribute__((ext_vector_type(4)));

#define FLAGS_BYTES (128*256)
#define XPRING_E ((size_t)RX*768*16)      // bf16 elems per (g,l)
#define HRING_E  ((size_t)RH*16*256)      // bf16 elems per (g,l)
#define WS_XP_OFF ((size_t)FLAGS_BYTES)
#define WS_H_OFF  (WS_XP_OFF + (size_t)32*XPRING_E*2)
#define WS_HF_OFF (WS_H_OFF  + (size_t)32*HRING_E*2)

struct Params {
  const int* tokens;
  const float* emb;
  const float* Wx[4];
  const float* Wh[4];
  const float* bx[4];
  const float* bh[4];
  uint8_t* ws;
};

#define SCOPE_AGENT __HIP_MEMORY_SCOPE_AGENT

__device__ __forceinline__ uint32_t* flagp(uint8_t* ws, int kind, int g, int l){
  return (uint32_t*)(ws + ((size_t)(kind*32 + g*4 + l) * 256));
}
__device__ __forceinline__ uint32_t aload(uint32_t* p){
  return __hip_atomic_load(p, __ATOMIC_RELAXED, SCOPE_AGENT);
}
__device__ __forceinline__ void astore(uint32_t* p, uint32_t v){
  __hip_atomic_store(p, v, __ATOMIC_RELAXED, SCOPE_AGENT);
}
// Wide coherent (coherence-point) data-plane ops: bypass L1/L2 via sc0 sc1.
__device__ __forceinline__ void st_coh_b64(void* p, unsigned long long v){
  asm volatile("global_store_dwordx2 %0, %1, off sc0 sc1" :: "v"(p), "v"(v) : "memory");
}
__device__ __forceinline__ void st_coh_b128(void* p, i32x4 v){
  asm volatile("global_store_dwordx4 %0, %1, off sc0 sc1" :: "v"(p), "v"(v) : "memory");
}
__device__ __forceinline__ unsigned long long ld_coh_b64(const void* p){
  unsigned long long r;
  asm volatile("global_load_dwordx2 %0, %1, off sc0 sc1" : "=v"(r) : "v"(p));
  return r;
}
__device__ __forceinline__ i32x4 ld_coh_b128(const void* p){
  i32x4 r;
  asm volatile("global_load_dwordx4 %0, %1, off sc0 sc1" : "=v"(r) : "v"(p));
  return r;
}
__device__ __forceinline__ void wait_vm0(){
  asm volatile("s_waitcnt vmcnt(0)" ::: "memory");
}
__device__ __forceinline__ unsigned short f2b(float f){
  __bf16 b = (__bf16)f; unsigned short u; __builtin_memcpy(&u, &b, 2); return u;
}
__device__ __forceinline__ float b2f(unsigned short u){
  __bf16 b; __builtin_memcpy(&b, &u, 2); return (float)b;
}
__device__ __forceinline__ f32x4 up4(unsigned long long q){
  f32x4 r;
  #pragma unroll
  for (int i=0;i<4;++i) r[i] = b2f((unsigned short)(q >> (16*i)));
  return r;
}
__device__ __forceinline__ unsigned long long pk4(f32x4 v){
  unsigned long long q = 0;
  #pragma unroll
  for (int i=0;i<4;++i) q |= ((unsigned long long)f2b(v[i])) << (16*i);
  return q;
}
__device__ __forceinline__ float sigf(float x){ return 1.f/(1.f + __expf(-x)); }
__device__ __forceinline__ float tanh_(float x){ return 2.f/(1.f + __expf(-2.f*x)) - 1.f; }

__global__ __launch_bounds__(512, 2) void gru_pipeline(Params p){
  const int bid = blockIdx.x;
  const int g = bid >> 3;          // group: samples [16g, 16g+16)
  const int s = bid & 7;           // stage slot
  const int l = s >> 1;            // layer
  const bool isXp = (s & 1) == 0;
  const int tid = threadIdx.x;
  const int w = tid >> 6;          // wave 0..7
  const int lane = tid & 63;
  const int lg = lane >> 4;        // k-subgroup 0..3
  const int lc = lane & 15;        // row/col selector

  __shared__ int dead;
  __shared__ __align__(16) unsigned short h_stage[2][16*256]; // xp A double-buffer
  __shared__ __align__(16) unsigned short h_lds[16*256];      // rec h state
  if (tid == 0) dead = 0;
  int budget = 1 << 22;

  if (isXp) {
    // ---------------- XP stage: xp = x @ Wx + (bx [+bh for z/r]) ----------------
    const float* W = p.Wx[l];
    bf16x8 wx[6][8];               // wave owns cols [w*96, w*96+96)
    #pragma unroll
    for (int nt=0; nt<6; ++nt){
      const int col = w*96 + nt*16 + lc;
      #pragma unroll
      for (int kt=0; kt<8; ++kt){
        const int k0 = kt*32 + lg*8;
        bf16x8 v;
        #pragma unroll
        for (int e=0; e<8; ++e) v[e] = (__bf16)W[(size_t)(k0+e)*768 + col];
        wx[nt][kt] = v;
      }
    }
    float bias[6];
    #pragma unroll
    for (int nt=0; nt<6; ++nt){
      const int col = w*96 + nt*16 + lc;
      bias[nt] = p.bx[l][col] + (col < 512 ? p.bh[l][col] : 0.f); // fold bh into z/r
    }
    uint32_t* prodXp = flagp(p.ws, 0, g, l);
    uint32_t* prodH  = (l>0) ? flagp(p.ws, 1, g, l-1) : nullptr;
    uint32_t* consXp = flagp(p.ws, 2, g, l);
    uint32_t* consH  = (l>0) ? flagp(p.ws, 3, g, l-1) : nullptr;
    __bf16* xr = (__bf16*)(p.ws + WS_XP_OFF) + (size_t)(g*4+l)*XPRING_E;
    const __bf16* hr = (l>0) ? ((const __bf16*)(p.ws + WS_H_OFF) + (size_t)(g*4+(l-1))*HRING_E) : nullptr;
    uint32_t consSeen = 0, prodSeen = 0;
    const int sm = tid >> 5, sc = tid & 31;   // staging row 0..15, chunk 0..31

    // prologue: stage slot 0 into buf 0 (visible to all waves at loop-top sync)
    if (l > 0){
      if (tid == 0){
        while (prodSeen < 1u){
          prodSeen = aload(prodH);
          if (prodSeen < 1u){ if(--budget<0){dead=1;break;} __builtin_amdgcn_s_sleep(2); }
        }
      }
      __syncthreads();
      if (!dead){
        i32x4 v = ld_coh_b128(hr + (size_t)sm*256 + sc*8);
        wait_vm0(); __builtin_amdgcn_sched_barrier(0);
        *(i32x4*)&h_stage[0][(sm*256 + sc*8) ^ ((sm&7)<<3)] = v;
      }
    } else {
      const int tok = p.tokens[(size_t)(g*16+sm)*TT];
      const float* er = p.emb + (size_t)tok*256 + sc*8;
      const float4 u0 = *(const float4*)er;
      const float4 u1 = *(const float4*)(er+4);
      bf16x8 v;
      v[0]=(__bf16)u0.x; v[1]=(__bf16)u0.y; v[2]=(__bf16)u0.z; v[3]=(__bf16)u0.w;
      v[4]=(__bf16)u1.x; v[5]=(__bf16)u1.y; v[6]=(__bf16)u1.z; v[7]=(__bf16)u1.w;
      *(bf16x8*)&h_stage[0][(sm*256 + sc*8) ^ ((sm&7)<<3)] = v;
    }

    for (int t=0; t<TT; ++t){
      if (tid == 0){
        if (l > 0){
          const uint32_t need = (uint32_t)((t+2 < TT) ? t+2 : TT);  // slot t+1 ready
          while (prodSeen < need){
            prodSeen = aload(prodH);
            if (prodSeen < need){ if(--budget<0){dead=1;break;} __builtin_amdgcn_s_sleep(2); }
          }
        }
        if (t >= RX){
          const uint32_t need2 = (uint32_t)(t - RX + 1);
          while (consSeen < need2){
            consSeen = aload(consXp);
            if (consSeen < need2){ if(--budget<0){dead=1;break;} __builtin_amdgcn_s_sleep(2); }
          }
        }
      }
      __syncthreads();              // drains prev-iter slot stores (vmcnt0 @ barrier)
      if (dead) break;
      if (tid == 0 && t > 0){
        astore(prodXp, (uint32_t)t);                 // slots < t ready & drained
        if (l > 0) astore(consH, (uint32_t)(t+1));   // h slots <= t read-retired
      }

      // prefetch next A (slot t+1) — latency hides under MFMA
      i32x4 stg;
      const bool haveStg = (l > 0) && (t+1 < TT);
      if (haveStg){
        stg = ld_coh_b128(hr + (size_t)((t+1)&(RH-1))*16*256 + sm*256 + sc*8);
      } else if (l == 0 && t+1 < TT){
        const int tok = p.tokens[(size_t)(g*16+sm)*TT + (t+1)];
        const float* er = p.emb + (size_t)tok*256 + sc*8;
        const float4 u0 = *(const float4*)er;
        const float4 u1 = *(const float4*)(er+4);
        bf16x8 v;
        v[0]=(__bf16)u0.x; v[1]=(__bf16)u0.y; v[2]=(__bf16)u0.z; v[3]=(__bf16)u0.w;
        v[4]=(__bf16)u1.x; v[5]=(__bf16)u1.y; v[6]=(__bf16)u1.z; v[7]=(__bf16)u1.w;
        *(bf16x8*)&h_stage[(t+1)&1][(sm*256 + sc*8) ^ ((sm&7)<<3)] = v;
      }

      // A-frags from staged LDS buffer (t&1) + MFMA
      const unsigned short* hsrc = h_stage[t&1];
      f32x4 acc[6];
      #pragma unroll
      for (int nt=0; nt<6; ++nt) acc[nt] = (f32x4){bias[nt],bias[nt],bias[nt],bias[nt]};
      #pragma unroll
      for (int kt=0; kt<8; ++kt){
        const bf16x8 a = *(const bf16x8*)&hsrc[(lc*256 + kt*32 + lg*8) ^ ((lc&7)<<3)];
        #pragma unroll
        for (int nt=0; nt<6; ++nt)
          acc[nt] = __builtin_amdgcn_mfma_f32_16x16x32_bf16(a, wx[nt][kt], acc[nt], 0, 0, 0);
      }
      if (haveStg){
        wait_vm0(); __builtin_amdgcn_sched_barrier(0);
        *(i32x4*)&h_stage[(t+1)&1][(sm*256 + sc*8) ^ ((sm&7)<<3)] = stg;
      }
      // store xp slot t: layout [slot][col][m], coherent 8B per tile
      __bf16* dst = xr + (size_t)(t&(RX-1))*768*16;
      #pragma unroll
      for (int nt=0; nt<6; ++nt){
        const int col = w*96 + nt*16 + lc;
        st_coh_b64(dst + col*16 + lg*4, pk4(acc[nt]));
      }
    }
    wait_vm0();
    __syncthreads();
    if (tid == 0 && !dead){
      astore(prodXp, (uint32_t)TT);
      if (l > 0) astore(consH, (uint32_t)TT);
    }
  } else {
    // ---------------- REC stage: rec = h @ Wh (+bh for hh); gates; h update ----------------
    const float* W = p.Wh[l];
    bf16x8 wh[6][8];   // wave owns hidden slice [w*32, w*32+32): nt = 2*G+q, G:0=z,1=r,2=hh
    #pragma unroll
    for (int nt=0; nt<6; ++nt){
      const int col = 256*(nt>>1) + w*32 + 16*(nt&1) + lc;
      #pragma unroll
      for (int kt=0; kt<8; ++kt){
        const int k0 = kt*32 + lg*8;
        bf16x8 v;
        #pragma unroll
        for (int e=0; e<8; ++e) v[e] = (__bf16)W[(size_t)(k0+e)*768 + col];
        wh[nt][kt] = v;
      }
    }
    float bhh[2];
    #pragma unroll
    for (int q=0; q<2; ++q) bhh[q] = p.bh[l][512 + w*32 + 16*q + lc];

    uint32_t* prodXp = flagp(p.ws, 0, g, l);
    uint32_t* prodH  = (l<3) ? flagp(p.ws, 1, g, l) : nullptr;
    uint32_t* consXp = flagp(p.ws, 2, g, l);
    uint32_t* consH  = (l<3) ? flagp(p.ws, 3, g, l) : nullptr;
    const __bf16* xr = (const __bf16*)(p.ws + WS_XP_OFF) + (size_t)(g*4+l)*XPRING_E;
    __bf16* hrw = (l<3) ? ((__bf16*)(p.ws + WS_H_OFF) + (size_t)(g*4+l)*HRING_E) : nullptr;
    float* hf = (float*)(p.ws + WS_HF_OFF);

    for (int i=tid; i<2048; i+=512) ((uint32_t*)h_lds)[i] = 0;
    f32x4 hprev[2] = {(f32x4){0.f,0.f,0.f,0.f},(f32x4){0.f,0.f,0.f,0.f}};
    uint32_t consSeen = 0, prodSeen = 0;

    for (int t=0; t<TT; ++t){
      if (tid == 0){
        while (prodSeen < (uint32_t)(t+1)){
          prodSeen = aload(prodXp);
          if (prodSeen < (uint32_t)(t+1)){ if(--budget<0){dead=1;break;} __builtin_amdgcn_s_sleep(2); }
        }
        if (l < 3 && t > RH){
          while (consSeen < (uint32_t)(t - RH)){
            consSeen = aload(consH);
            if (consSeen < (uint32_t)(t - RH)){ if(--budget<0){dead=1;break;} __builtin_amdgcn_s_sleep(2); }
          }
        }
      }
      __syncthreads();
      if (dead) break;

      // xp loads for slot t (coherent, deferred use in gates -> latency under MFMA)
      const __bf16* xb = xr + (size_t)(t&(RX-1))*768*16;
      unsigned long long xpld[6];
      #pragma unroll
      for (int nt=0; nt<6; ++nt){
        const int col = 256*(nt>>1) + w*32 + 16*(nt&1) + lc;
        xpld[nt] = ld_coh_b64(xb + col*16 + lg*4);
      }
      // export h(t-1): wave-dedup, 16B/lane, linear ring layout [slot][row][k]
      if (l < 3 && t > 0){
        const i32x4 ev = *(const i32x4*)&h_lds[(lc*256 + w*32 + lg*8) ^ ((lc&7)<<3)];
        st_coh_b128(hrw + (size_t)((t-1)&(RH-1))*16*256 + lc*256 + w*32 + lg*8, ev);
      }
      // MFMA over K=256, acc starts at 0 (no global dependency)
      f32x4 acc[6];
      #pragma unroll
      for (int nt=0; nt<6; ++nt) acc[nt] = (f32x4){0.f,0.f,0.f,0.f};
      #pragma unroll
      for (int kt=0; kt<8; ++kt){
        const bf16x8 a = *(const bf16x8*)&h_lds[(lc*256 + kt*32 + lg*8) ^ ((lc&7)<<3)];
        #pragma unroll
        for (int nt=0; nt<6; ++nt)
          acc[nt] = __builtin_amdgcn_mfma_f32_16x16x32_bf16(a, wh[nt][kt], acc[nt], 0, 0, 0);
      }
      wait_vm0(); __builtin_amdgcn_sched_barrier(0);   // xpld ready; export acked
      // gates: z = sig(xz+rz), r = sig(xr+rr), hh = tanh(xh + r*(rh+bh_h))
      #pragma unroll
      for (int q=0; q<2; ++q){
        const f32x4 xz = up4(xpld[q]);
        const f32x4 xr_ = up4(xpld[2+q]);
        const f32x4 xh = up4(xpld[4+q]);
        #pragma unroll
        for (int e=0; e<4; ++e){
          const float z = sigf(xz[e] + acc[q][e]);
          const float r = sigf(xr_[e] + acc[2+q][e]);
          const float c = tanh_(xh[e] + r*(acc[4+q][e] + bhh[q]));
          hprev[q][e] = z*hprev[q][e] + (1.f - z)*c;
        }
      }
      __syncthreads();   // all LDS reads of h(t-1) complete
      #pragma unroll
      for (int q=0; q<2; ++q){
        const int j = w*32 + 16*q + lc;
        #pragma unroll
        for (int r2=0; r2<4; ++r2){
          const int m = lg*4 + r2;
          h_lds[(m*256 + j) ^ ((m&7)<<3)] = f2b(hprev[q][r2]);
        }
      }
      if (l == 3 && t == TT-1){
        #pragma unroll
        for (int q=0; q<2; ++q){
          const int j = w*32 + 16*q + lc;
          #pragma unroll
          for (int r2=0; r2<4; ++r2) hf[(size_t)(g*16 + lg*4 + r2)*256 + j] = hprev[q][r2];
        }
      }
      __syncthreads();
      if (tid == 0){
        if (l < 3 && t > 0) astore(prodH, (uint32_t)t);  // slots <= t-1 ready (drained)
        astore(consXp, (uint32_t)(t+1));                 // xp slot t retired
      }
    }
    if (!dead){
      if (l < 3){
        const i32x4 ev = *(const i32x4*)&h_lds[(lc*256 + w*32 + lg*8) ^ ((lc&7)<<3)];
        st_coh_b128(hrw + (size_t)((TT-1)&(RH-1))*16*256 + lc*256 + w*32 + lg*8, ev);
        wait_vm0();
        __syncthreads();
        if (tid == 0) astore(prodH, (uint32_t)TT);
      }
      if (tid == 0) astore(consXp, (uint32_t)TT);
    }
  }
}

// Final head: relu(h @ Wd1 + bd1) @ Wd2 + bd2 -> sigmoid. One block per sample.
__global__ __launch_bounds__(256) void dense_head(const float* __restrict__ hf,
    const float* __restrict__ Wd1, const float* __restrict__ bd1,
    const float* __restrict__ Wd2, const float* __restrict__ bd2,
    float* __restrict__ out){
  const int m = blockIdx.x;
  const int n = threadIdx.x;
  __shared__ float hs[256];
  __shared__ float red[256];
  hs[n] = hf[(size_t)m*256 + n];
  __syncthreads();
  float acc = bd1[n];
  #pragma unroll 8
  for (int k=0; k<256; ++k) acc = fmaf(hs[k], Wd1[(size_t)k*256 + n], acc);
  const float rl = fmaxf(acc, 0.f);
  red[n] = rl * Wd2[n];
  __syncthreads();
  for (int off=128; off>0; off>>=1){
    if (n < off) red[n] += red[n+off];
    __syncthreads();
  }
  if (n == 0) out[m] = 1.f/(1.f + __expf(-(red[0] + bd2[0])));
}

extern "C" void kernel_launch(void* const* d_in, const int* in_sizes, int n_in,
                              void* d_out, int out_size, void* d_ws, size_t ws_size,
                              hipStream_t stream){
  (void)in_sizes; (void)n_in; (void)out_size; (void)ws_size;
  Params p;
  p.tokens = (const int*)d_in[0];
  p.emb    = (const float*)d_in[1];
  for (int l=0; l<4; ++l){
    p.Wx[l] = (const float*)d_in[2+4*l];
    p.Wh[l] = (const float*)d_in[3+4*l];
    p.bx[l] = (const float*)d_in[4+4*l];
    p.bh[l] = (const float*)d_in[5+4*l];
  }
  p.ws = (uint8_t*)d_ws;
  hipMemsetAsync(d_ws, 0, FLAGS_BYTES, stream);           // zero flags each launch
  gru_pipeline<<<dim3(64), dim3(512), 0, stream>>>(p);
  dense_head<<<dim3(128), dim3(256), 0, stream>>>(
      (const float*)((uint8_t*)d_ws + WS_HF_OFF),
      (const float*)d_in[18], (const float*)d_in[19],
      (const float*)d_in[20], (const float*)d_in[21],
      (float*)d_out);
}

// Round 3
// 2892.579 us; speedup vs baseline: 1.7871x; 1.0038x over previous
//
#include <hip/hip_runtime.h>
#include <stdint.h>

// GRUClassifier: B=128, T=512, V=50000, D=U=256, 3U=768
// Persistent pipelined kernel, 64 blocks = 8 groups (16 samples) x 8 stages
// (xp0,rec0,...,xp3,rec3). Flags: 4B agent atomics (tid0 only). Ring DATA:
// wide coherent loads/stores (global_*_dwordx2/x4 sc0 sc1).
// R3 change: amdgpu_waves_per_eu(2,2) -> 256-VGPR budget so the 192-VGPR
// resident weight fragments stop spilling to scratch (r2: VGPR=128, 384KB/step
// L2 scratch re-reads ~= 2.8us/step, the dominant cost).

#define TT 512
#define RX 16   // xp ring depth (steps)
#define RH 64   // h ring depth (steps)

typedef __bf16 bf16x8 __attribute__((ext_vector_type(8)));
typedef float f32x4 __attribute__((ext_vector_type(4)));
typedef int i32x4 __attribute__((ext_vector_type(4)));

#define FLAGS_BYTES (128*256)
#define XPRING_E ((size_t)RX*768*16)      // bf16 elems per (g,l)
#define HRING_E  ((size_t)RH*16*256)      // bf16 elems per (g,l)
#define WS_XP_OFF ((size_t)FLAGS_BYTES)
#define WS_H_OFF  (WS_XP_OFF + (size_t)32*XPRING_E*2)
#define WS_HF_OFF (WS_H_OFF  + (size_t)32*HRING_E*2)

struct Params {
  const int* tokens;
  const float* emb;
  const float* Wx[4];
  const float* Wh[4];
  const float* bx[4];
  const float* bh[4];
  uint8_t* ws;
};

#define SCOPE_AGENT __HIP_MEMORY_SCOPE_AGENT

__device__ __forceinline__ uint32_t* flagp(uint8_t* ws, int kind, int g, int l){
  return (uint32_t*)(ws + ((size_t)(kind*32 + g*4 + l) * 256));
}
__device__ __forceinline__ uint32_t aload(uint32_t* p){
  return __hip_atomic_load(p, __ATOMIC_RELAXED, SCOPE_AGENT);
}
__device__ __forceinline__ void astore(uint32_t* p, uint32_t v){
  __hip_atomic_store(p, v, __ATOMIC_RELAXED, SCOPE_AGENT);
}
// Wide coherent (coherence-point) data-plane ops: bypass L1/L2 via sc0 sc1.
__device__ __forceinline__ void st_coh_b64(void* p, unsigned long long v){
  asm volatile("global_store_dwordx2 %0, %1, off sc0 sc1" :: "v"(p), "v"(v) : "memory");
}
__device__ __forceinline__ void st_coh_b128(void* p, i32x4 v){
  asm volatile("global_store_dwordx4 %0, %1, off sc0 sc1" :: "v"(p), "v"(v) : "memory");
}
__device__ __forceinline__ unsigned long long ld_coh_b64(const void* p){
  unsigned long long r;
  asm volatile("global_load_dwordx2 %0, %1, off sc0 sc1" : "=v"(r) : "v"(p));
  return r;
}
__device__ __forceinline__ i32x4 ld_coh_b128(const void* p){
  i32x4 r;
  asm volatile("global_load_dwordx4 %0, %1, off sc0 sc1" : "=v"(r) : "v"(p));
  return r;
}
__device__ __forceinline__ void wait_vm0(){
  asm volatile("s_waitcnt vmcnt(0)" ::: "memory");
}
__device__ __forceinline__ unsigned short f2b(float f){
  __bf16 b = (__bf16)f; unsigned short u; __builtin_memcpy(&u, &b, 2); return u;
}
__device__ __forceinline__ float b2f(unsigned short u){
  __bf16 b; __builtin_memcpy(&b, &u, 2); return (float)b;
}
__device__ __forceinline__ f32x4 up4(unsigned long long q){
  f32x4 r;
  #pragma unroll
  for (int i=0;i<4;++i) r[i] = b2f((unsigned short)(q >> (16*i)));
  return r;
}
__device__ __forceinline__ unsigned long long pk4(f32x4 v){
  unsigned long long q = 0;
  #pragma unroll
  for (int i=0;i<4;++i) q |= ((unsigned long long)f2b(v[i])) << (16*i);
  return q;
}
__device__ __forceinline__ float sigf(float x){ return 1.f/(1.f + __expf(-x)); }
__device__ __forceinline__ float tanh_(float x){ return 2.f/(1.f + __expf(-2.f*x)) - 1.f; }

__global__ __attribute__((amdgpu_waves_per_eu(2,2))) __launch_bounds__(512)
void gru_pipeline(Params p){
  const int bid = blockIdx.x;
  const int g = bid >> 3;          // group: samples [16g, 16g+16)
  const int s = bid & 7;           // stage slot
  const int l = s >> 1;            // layer
  const bool isXp = (s & 1) == 0;
  const int tid = threadIdx.x;
  const int w = tid >> 6;          // wave 0..7
  const int lane = tid & 63;
  const int lg = lane >> 4;        // k-subgroup 0..3
  const int lc = lane & 15;        // row/col selector

  __shared__ int dead;
  __shared__ __align__(16) unsigned short h_stage[2][16*256]; // xp A double-buffer
  __shared__ __align__(16) unsigned short h_lds[16*256];      // rec h state
  if (tid == 0) dead = 0;
  int budget = 1 << 22;

  if (isXp) {
    // ---------------- XP stage: xp = x @ Wx + (bx [+bh for z/r]) ----------------
    const float* W = p.Wx[l];
    bf16x8 wx[6][8];               // wave owns cols [w*96, w*96+96) -- VGPR-resident
    #pragma unroll
    for (int nt=0; nt<6; ++nt){
      const int col = w*96 + nt*16 + lc;
      #pragma unroll
      for (int kt=0; kt<8; ++kt){
        const int k0 = kt*32 + lg*8;
        bf16x8 v;
        #pragma unroll
        for (int e=0; e<8; ++e) v[e] = (__bf16)W[(size_t)(k0+e)*768 + col];
        wx[nt][kt] = v;
      }
    }
    float bias[6];
    #pragma unroll
    for (int nt=0; nt<6; ++nt){
      const int col = w*96 + nt*16 + lc;
      bias[nt] = p.bx[l][col] + (col < 512 ? p.bh[l][col] : 0.f); // fold bh into z/r
    }
    uint32_t* prodXp = flagp(p.ws, 0, g, l);
    uint32_t* prodH  = (l>0) ? flagp(p.ws, 1, g, l-1) : nullptr;
    uint32_t* consXp = flagp(p.ws, 2, g, l);
    uint32_t* consH  = (l>0) ? flagp(p.ws, 3, g, l-1) : nullptr;
    __bf16* xr = (__bf16*)(p.ws + WS_XP_OFF) + (size_t)(g*4+l)*XPRING_E;
    const __bf16* hr = (l>0) ? ((const __bf16*)(p.ws + WS_H_OFF) + (size_t)(g*4+(l-1))*HRING_E) : nullptr;
    uint32_t consSeen = 0, prodSeen = 0;
    const int sm = tid >> 5, sc = tid & 31;   // staging row 0..15, chunk 0..31

    // prologue: stage slot 0 into buf 0 (visible to all waves at loop-top sync)
    if (l > 0){
      if (tid == 0){
        while (prodSeen < 1u){
          prodSeen = aload(prodH);
          if (prodSeen < 1u){ if(--budget<0){dead=1;break;} __builtin_amdgcn_s_sleep(2); }
        }
      }
      __syncthreads();
      if (!dead){
        i32x4 v = ld_coh_b128(hr + (size_t)sm*256 + sc*8);
        wait_vm0(); __builtin_amdgcn_sched_barrier(0);
        *(i32x4*)&h_stage[0][(sm*256 + sc*8) ^ ((sm&7)<<3)] = v;
      }
    } else {
      const int tok = p.tokens[(size_t)(g*16+sm)*TT];
      const float* er = p.emb + (size_t)tok*256 + sc*8;
      const float4 u0 = *(const float4*)er;
      const float4 u1 = *(const float4*)(er+4);
      bf16x8 v;
      v[0]=(__bf16)u0.x; v[1]=(__bf16)u0.y; v[2]=(__bf16)u0.z; v[3]=(__bf16)u0.w;
      v[4]=(__bf16)u1.x; v[5]=(__bf16)u1.y; v[6]=(__bf16)u1.z; v[7]=(__bf16)u1.w;
      *(bf16x8*)&h_stage[0][(sm*256 + sc*8) ^ ((sm&7)<<3)] = v;
    }

    for (int t=0; t<TT; ++t){
      if (tid == 0){
        if (l > 0){
          const uint32_t need = (uint32_t)((t+2 < TT) ? t+2 : TT);  // slot t+1 ready
          while (prodSeen < need){
            prodSeen = aload(prodH);
            if (prodSeen < need){ if(--budget<0){dead=1;break;} __builtin_amdgcn_s_sleep(2); }
          }
        }
        if (t >= RX){
          const uint32_t need2 = (uint32_t)(t - RX + 1);
          while (consSeen < need2){
            consSeen = aload(consXp);
            if (consSeen < need2){ if(--budget<0){dead=1;break;} __builtin_amdgcn_s_sleep(2); }
          }
        }
      }
      __syncthreads();              // drains prev-iter slot stores (vmcnt0 @ barrier)
      if (dead) break;
      if (tid == 0 && t > 0){
        astore(prodXp, (uint32_t)t);                 // slots < t ready & drained
        if (l > 0) astore(consH, (uint32_t)(t+1));   // h slots <= t read-retired
      }

      // prefetch next A (slot t+1) — latency hides under MFMA
      i32x4 stg;
      const bool haveStg = (l > 0) && (t+1 < TT);
      if (haveStg){
        stg = ld_coh_b128(hr + (size_t)((t+1)&(RH-1))*16*256 + sm*256 + sc*8);
      } else if (l == 0 && t+1 < TT){
        const int tok = p.tokens[(size_t)(g*16+sm)*TT + (t+1)];
        const float* er = p.emb + (size_t)tok*256 + sc*8;
        const float4 u0 = *(const float4*)er;
        const float4 u1 = *(const float4*)(er+4);
        bf16x8 v;
        v[0]=(__bf16)u0.x; v[1]=(__bf16)u0.y; v[2]=(__bf16)u0.z; v[3]=(__bf16)u0.w;
        v[4]=(__bf16)u1.x; v[5]=(__bf16)u1.y; v[6]=(__bf16)u1.z; v[7]=(__bf16)u1.w;
        *(bf16x8*)&h_stage[(t+1)&1][(sm*256 + sc*8) ^ ((sm&7)<<3)] = v;
      }

      // A-frags from staged LDS buffer (t&1) + MFMA
      const unsigned short* hsrc = h_stage[t&1];
      f32x4 acc[6];
      #pragma unroll
      for (int nt=0; nt<6; ++nt) acc[nt] = (f32x4){bias[nt],bias[nt],bias[nt],bias[nt]};
      #pragma unroll
      for (int kt=0; kt<8; ++kt){
        const bf16x8 a = *(const bf16x8*)&hsrc[(lc*256 + kt*32 + lg*8) ^ ((lc&7)<<3)];
        #pragma unroll
        for (int nt=0; nt<6; ++nt)
          acc[nt] = __builtin_amdgcn_mfma_f32_16x16x32_bf16(a, wx[nt][kt], acc[nt], 0, 0, 0);
      }
      if (haveStg){
        wait_vm0(); __builtin_amdgcn_sched_barrier(0);
        *(i32x4*)&h_stage[(t+1)&1][(sm*256 + sc*8) ^ ((sm&7)<<3)] = stg;
      }
      // store xp slot t: layout [slot][col][m], coherent 8B per tile
      __bf16* dst = xr + (size_t)(t&(RX-1))*768*16;
      #pragma unroll
      for (int nt=0; nt<6; ++nt){
        const int col = w*96 + nt*16 + lc;
        st_coh_b64(dst + col*16 + lg*4, pk4(acc[nt]));
      }
    }
    wait_vm0();
    __syncthreads();
    if (tid == 0 && !dead){
      astore(prodXp, (uint32_t)TT);
      if (l > 0) astore(consH, (uint32_t)TT);
    }
  } else {
    // ---------------- REC stage: rec = h @ Wh (+bh for hh); gates; h update ----------------
    const float* W = p.Wh[l];
    bf16x8 wh[6][8];   // wave owns hidden slice [w*32, w*32+32) -- VGPR-resident
    #pragma unroll
    for (int nt=0; nt<6; ++nt){
      const int col = 256*(nt>>1) + w*32 + 16*(nt&1) + lc;
      #pragma unroll
      for (int kt=0; kt<8; ++kt){
        const int k0 = kt*32 + lg*8;
        bf16x8 v;
        #pragma unroll
        for (int e=0; e<8; ++e) v[e] = (__bf16)W[(size_t)(k0+e)*768 + col];
        wh[nt][kt] = v;
      }
    }
    float bhh[2];
    #pragma unroll
    for (int q=0; q<2; ++q) bhh[q] = p.bh[l][512 + w*32 + 16*q + lc];

    uint32_t* prodXp = flagp(p.ws, 0, g, l);
    uint32_t* prodH  = (l<3) ? flagp(p.ws, 1, g, l) : nullptr;
    uint32_t* consXp = flagp(p.ws, 2, g, l);
    uint32_t* consH  = (l<3) ? flagp(p.ws, 3, g, l) : nullptr;
    const __bf16* xr = (const __bf16*)(p.ws + WS_XP_OFF) + (size_t)(g*4+l)*XPRING_E;
    __bf16* hrw = (l<3) ? ((__bf16*)(p.ws + WS_H_OFF) + (size_t)(g*4+l)*HRING_E) : nullptr;
    float* hf = (float*)(p.ws + WS_HF_OFF);

    for (int i=tid; i<2048; i+=512) ((uint32_t*)h_lds)[i] = 0;
    f32x4 hprev[2] = {(f32x4){0.f,0.f,0.f,0.f},(f32x4){0.f,0.f,0.f,0.f}};
    uint32_t consSeen = 0, prodSeen = 0;

    for (int t=0; t<TT; ++t){
      if (tid == 0){
        while (prodSeen < (uint32_t)(t+1)){
          prodSeen = aload(prodXp);
          if (prodSeen < (uint32_t)(t+1)){ if(--budget<0){dead=1;break;} __builtin_amdgcn_s_sleep(2); }
        }
        if (l < 3 && t > RH){
          while (consSeen < (uint32_t)(t - RH)){
            consSeen = aload(consH);
            if (consSeen < (uint32_t)(t - RH)){ if(--budget<0){dead=1;break;} __builtin_amdgcn_s_sleep(2); }
          }
        }
      }
      __syncthreads();
      if (dead) break;

      // xp loads for slot t (coherent, deferred use in gates -> latency under MFMA)
      const __bf16* xb = xr + (size_t)(t&(RX-1))*768*16;
      unsigned long long xpld[6];
      #pragma unroll
      for (int nt=0; nt<6; ++nt){
        const int col = 256*(nt>>1) + w*32 + 16*(nt&1) + lc;
        xpld[nt] = ld_coh_b64(xb + col*16 + lg*4);
      }
      // export h(t-1): wave-dedup, 16B/lane, linear ring layout [slot][row][k]
      if (l < 3 && t > 0){
        const i32x4 ev = *(const i32x4*)&h_lds[(lc*256 + w*32 + lg*8) ^ ((lc&7)<<3)];
        st_coh_b128(hrw + (size_t)((t-1)&(RH-1))*16*256 + lc*256 + w*32 + lg*8, ev);
      }
      // MFMA over K=256, acc starts at 0 (no global dependency)
      f32x4 acc[6];
      #pragma unroll
      for (int nt=0; nt<6; ++nt) acc[nt] = (f32x4){0.f,0.f,0.f,0.f};
      #pragma unroll
      for (int kt=0; kt<8; ++kt){
        const bf16x8 a = *(const bf16x8*)&h_lds[(lc*256 + kt*32 + lg*8) ^ ((lc&7)<<3)];
        #pragma unroll
        for (int nt=0; nt<6; ++nt)
          acc[nt] = __builtin_amdgcn_mfma_f32_16x16x32_bf16(a, wh[nt][kt], acc[nt], 0, 0, 0);
      }
      wait_vm0(); __builtin_amdgcn_sched_barrier(0);   // xpld ready; export acked
      // gates: z = sig(xz+rz), r = sig(xr+rr), hh = tanh(xh + r*(rh+bh_h))
      #pragma unroll
      for (int q=0; q<2; ++q){
        const f32x4 xz = up4(xpld[q]);
        const f32x4 xr_ = up4(xpld[2+q]);
        const f32x4 xh = up4(xpld[4+q]);
        #pragma unroll
        for (int e=0; e<4; ++e){
          const float z = sigf(xz[e] + acc[q][e]);
          const float r = sigf(xr_[e] + acc[2+q][e]);
          const float c = tanh_(xh[e] + r*(acc[4+q][e] + bhh[q]));
          hprev[q][e] = z*hprev[q][e] + (1.f - z)*c;
        }
      }
      __syncthreads();   // all LDS reads of h(t-1) complete
      #pragma unroll
      for (int q=0; q<2; ++q){
        const int j = w*32 + 16*q + lc;
        #pragma unroll
        for (int r2=0; r2<4; ++r2){
          const int m = lg*4 + r2;
          h_lds[(m*256 + j) ^ ((m&7)<<3)] = f2b(hprev[q][r2]);
        }
      }
      if (l == 3 && t == TT-1){
        #pragma unroll
        for (int q=0; q<2; ++q){
          const int j = w*32 + 16*q + lc;
          #pragma unroll
          for (int r2=0; r2<4; ++r2) hf[(size_t)(g*16 + lg*4 + r2)*256 + j] = hprev[q][r2];
        }
      }
      __syncthreads();
      if (tid == 0){
        if (l < 3 && t > 0) astore(prodH, (uint32_t)t);  // slots <= t-1 ready (drained)
        astore(consXp, (uint32_t)(t+1));                 // xp slot t retired
      }
    }
    if (!dead){
      if (l < 3){
        const i32x4 ev = *(const i32x4*)&h_lds[(lc*256 + w*32 + lg*8) ^ ((lc&7)<<3)];
        st_coh_b128(hrw + (size_t)((TT-1)&(RH-1))*16*256 + lc*256 + w*32 + lg*8, ev);
        wait_vm0();
        __syncthreads();
        if (tid == 0) astore(prodH, (uint32_t)TT);
      }
      if (tid == 0) astore(consXp, (uint32_t)TT);
    }
  }
}

// Final head: relu(h @ Wd1 + bd1) @ Wd2 + bd2 -> sigmoid. One block per sample.
__global__ __launch_bounds__(256) void dense_head(const float* __restrict__ hf,
    const float* __restrict__ Wd1, const float* __restrict__ bd1,
    const float* __restrict__ Wd2, const float* __restrict__ bd2,
    float* __restrict__ out){
  const int m = blockIdx.x;
  const int n = threadIdx.x;
  __shared__ float hs[256];
  __shared__ float red[256];
  hs[n] = hf[(size_t)m*256 + n];
  __syncthreads();
  float acc = bd1[n];
  #pragma unroll 8
  for (int k=0; k<256; ++k) acc = fmaf(hs[k], Wd1[(size_t)k*256 + n], acc);
  const float rl = fmaxf(acc, 0.f);
  red[n] = rl * Wd2[n];
  __syncthreads();
  for (int off=128; off>0; off>>=1){
    if (n < off) red[n] += red[n+off];
    __syncthreads();
  }
  if (n == 0) out[m] = 1.f/(1.f + __expf(-(red[0] + bd2[0])));
}

extern "C" void kernel_launch(void* const* d_in, const int* in_sizes, int n_in,
                              void* d_out, int out_size, void* d_ws, size_t ws_size,
                              hipStream_t stream){
  (void)in_sizes; (void)n_in; (void)out_size; (void)ws_size;
  Params p;
  p.tokens = (const int*)d_in[0];
  p.emb    = (const float*)d_in[1];
  for (int l=0; l<4; ++l){
    p.Wx[l] = (const float*)d_in[2+4*l];
    p.Wh[l] = (const float*)d_in[3+4*l];
    p.bx[l] = (const float*)d_in[4+4*l];
    p.bh[l] = (const float*)d_in[5+4*l];
  }
  p.ws = (uint8_t*)d_ws;
  hipMemsetAsync(d_ws, 0, FLAGS_BYTES, stream);           // zero flags each launch
  gru_pipeline<<<dim3(64), dim3(512), 0, stream>>>(p);
  dense_head<<<dim3(128), dim3(256), 0, stream>>>(
      (const float*)((uint8_t*)d_ws + WS_HF_OFF),
      (const float*)d_in[18], (const float*)d_in[19],
      (const float*)d_in[20], (const float*)d_in[21],
      (float*)d_out);
}